// Round 3
// baseline (311.363 us; speedup 1.0000x reference)
//
#include <hip/hip_runtime.h>
#include <hip/hip_bf16.h>
#include <cstdint>

typedef short short8 __attribute__((ext_vector_type(8)));
typedef __bf16 bf16x8 __attribute__((ext_vector_type(8)));
typedef float f32x4 __attribute__((ext_vector_type(4)));
typedef unsigned short u16;
typedef unsigned int u32;

#define B_  2
#define N_  4096
#define D_  2048
#define H_  8
#define DH_ 128
#define W_  512
#define M_  (B_*N_)      // 8192
#define INNER_ (H_*DH_)  // 1024

static __device__ __forceinline__ u16 f2bf(float f) {
  u32 u = __float_as_uint(f);
  u32 r = (u + 0x7fffu + ((u >> 16) & 1u)) >> 16;   // RNE
  return (u16)r;
}
static __device__ __forceinline__ float bf2f(u16 u) {
  return __uint_as_float(((u32)u) << 16);
}
static __device__ __forceinline__ f32x4 mfma16(short8 a, short8 b, f32x4 c) {
  return __builtin_amdgcn_mfma_f32_16x16x32_bf16(
      __builtin_bit_cast(bf16x8, a), __builtin_bit_cast(bf16x8, b), c, 0, 0, 0);
}

#define GLOAD_LDS16(g, s) \
  __builtin_amdgcn_global_load_lds((const __attribute__((address_space(1))) void*)(g), \
                                   (__attribute__((address_space(3))) void*)(s), 16, 0, 0)

// ---------------- convert f32 -> bf16 (x, Wq|Wkv concat, Wo) ----------------
__global__ __launch_bounds__(256) void cvt_kernel(
    const float* __restrict__ x, const float* __restrict__ Wq,
    const float* __restrict__ Wkv, const float* __restrict__ Wo,
    u16* __restrict__ xb, u16* __restrict__ Wcat, u16* __restrict__ Wob) {
  size_t i = ((size_t)blockIdx.x * 256 + threadIdx.x) * 8;
  const float* src; u16* dst; size_t off;
  const size_t SX = 16777216ul, SQ = 2097152ul, SKV = 4194304ul;
  if (i < SX)                { src = x;   dst = xb;             off = i; }
  else if (i < SX+SQ)        { src = Wq;  dst = Wcat;           off = i - SX; }
  else if (i < SX+SQ+SKV)    { src = Wkv; dst = Wcat + 2097152; off = i - SX - SQ; }
  else                       { src = Wo;  dst = Wob;            off = i - SX - SQ - SKV; }
  float4 a = *(const float4*)(src + off);
  float4 b = *(const float4*)(src + off + 4);
  short8 o;
  o[0]=(short)f2bf(a.x); o[1]=(short)f2bf(a.y); o[2]=(short)f2bf(a.z); o[3]=(short)f2bf(a.w);
  o[4]=(short)f2bf(b.x); o[5]=(short)f2bf(b.y); o[6]=(short)f2bf(b.z); o[7]=(short)f2bf(b.w);
  *(short8*)(dst + off) = o;
}

// ================= 256x256 8-phase bf16 GEMM, C = A(MxK) * Bw(NxK)^T ========
// 512 thr / 8 waves (2M x 4N). BK=64 split in two K-halves of 32.
// LDS: [buf][kh] 256x32 per operand, 128 KiB total.
// Counted vmcnt: two waits per tile, each targeting loads issued ~6 phases
// earlier (Kh1 of T protected at T.ph2; Kh0 of T+1 protected at T.ph4).
#define BARRIER() __builtin_amdgcn_s_barrier()
#define WAIT_LGKM0() do { asm volatile("s_waitcnt lgkmcnt(0)" ::: "memory"); \
                          __builtin_amdgcn_sched_barrier(0); } while(0)
#define WVM8 asm volatile("s_waitcnt vmcnt(8)" ::: "memory")
#define WVM4 asm volatile("s_waitcnt vmcnt(4)" ::: "memory")
#define WVM0 asm volatile("s_waitcnt vmcnt(0)" ::: "memory")
#define WNONE ((void)0)

// stage one 256x32 half-tile (16 KB): per thread 2 x global_load_lds(16B).
// LDS linear dest; source K-chunk pre-swizzled so reads can XOR-deswizzle.
#define STAGE_HALF(gbase, sreg) do { \
    const u16* _g = (gbase) + _cs; \
    GLOAD_LDS16(_g + (size_t)(wv*32 + (lane>>2))*K,      (sreg) + wv*1024); \
    GLOAD_LDS16(_g + (size_t)(wv*32 + 16 + (lane>>2))*K, (sreg) + wv*1024 + 512); \
  } while(0)

#define LOAD_AF(sreg, mfb) do { \
    _Pragma("unroll") for (int q = 0; q < 4; ++q) \
      af[q] = *(const short8*)((sreg) + (wm*128 + ((mfb)+q)*16 + l15)*32 + fch); \
  } while(0)
#define LOAD_BF(sreg) do { \
    _Pragma("unroll") for (int q = 0; q < 4; ++q) \
      bf[q] = *(const short8*)((sreg) + (wn*64 + q*16 + l15)*32 + fch); \
  } while(0)

#define PH_MFMA(mfb) do { \
    __builtin_amdgcn_s_setprio(1); \
    _Pragma("unroll") for (int q = 0; q < 4; ++q) \
      _Pragma("unroll") for (int nf = 0; nf < 4; ++nf) \
        acc[(mfb)+q][nf] = mfma16(af[q], bf[nf], acc[(mfb)+q][nf]); \
    __builtin_amdgcn_s_setprio(0); \
  } while(0)

// 4 phases of one K-tile T. SA_C/SB_C = current buf kh0 base (+8192 -> kh1);
// SA_N/SB_N = other buf. C1: stage T+1's Kh1 into other buf. C2: stage T+2's
// Kh0 into current buf. WB guards this tile's Kh1 reads (ph3); WA guards
// next tile's Kh0 reads (T+1.ph1). Steady-state counts = 8 (see derivation).
#define TILE4(T, SA_C, SB_C, SA_N, SB_N, C1, C2, WB, WA) do { \
    const u16* gAt = gA + (size_t)(T)*64; \
    const u16* gBt = gB + (size_t)(T)*64; \
    short8 af[4], bf[4]; \
    LOAD_AF(SA_C, 0); LOAD_BF(SB_C); \
    if (C1) STAGE_HALF(gAt + 96, (SA_N) + 8192); \
    BARRIER(); WAIT_LGKM0(); PH_MFMA(0); BARRIER(); \
    LOAD_AF(SA_C, 4); \
    if (C1) STAGE_HALF(gBt + 96, (SB_N) + 8192); \
    WB; \
    BARRIER(); WAIT_LGKM0(); PH_MFMA(4); BARRIER(); \
    LOAD_AF((SA_C) + 8192, 0); LOAD_BF((SB_C) + 8192); \
    if (C2) STAGE_HALF(gAt + 128, SA_C); \
    BARRIER(); WAIT_LGKM0(); PH_MFMA(0); BARRIER(); \
    LOAD_AF((SA_C) + 8192, 4); \
    if (C2) STAGE_HALF(gBt + 128, SB_C); \
    WA; \
    BARRIER(); WAIT_LGKM0(); PH_MFMA(4); BARRIER(); \
  } while(0)

template<int EPI>
__global__ __launch_bounds__(512, 2) void gemm256(
    const u16* __restrict__ A, const u16* __restrict__ Bw,
    u16* __restrict__ Dq, u16* __restrict__ Dk, u16* __restrict__ Dv,
    float* __restrict__ Cf, int Ncols, int K) {
  extern __shared__ u16 lds[];
  const int tid = threadIdx.x;
  const int lane = tid & 63, wv = tid >> 6;
  const int wm = wv >> 2, wn = wv & 3;
  const int l15 = lane & 15, l4 = lane >> 4;

  // bijective XCD swizzle (gridDim.x % 8 == 0); by fastest -> share B-panel
  const int nwg = gridDim.x;
  const int swz = (blockIdx.x & 7) * (nwg >> 3) + (blockIdx.x >> 3);
  const int by = swz & 31;                  // M/256 = 32 tiles
  const int bx = swz >> 5;
  const int m0 = by << 8, n0 = bx << 8;

  const u16* gA = A + (size_t)m0 * K;
  const u16* gB = Bw + (size_t)n0 * K;
  u16* sA0 = lds;                 // [buf][kh] stride 8192 u16 (16 KB)
  u16* sB0 = lds + 32768;

  const int _cs = ((lane & 3) ^ ((lane >> 3) & 3)) * 8;  // stage src pre-swizzle
  const int fch = (l4 ^ ((l15 >> 1) & 3)) * 8;           // frag read deswizzle

  f32x4 acc[8][4] = {};

  // prologue: t0 all 4 halves, t1 Kh0 halves; tile0 resident after vmcnt(4)
  STAGE_HALF(gA,      sA0);
  STAGE_HALF(gB,      sB0);
  STAGE_HALF(gA + 32, sA0 + 8192);
  STAGE_HALF(gB + 32, sB0 + 8192);
  STAGE_HALF(gA + 64, sA0 + 16384);
  STAGE_HALF(gB + 64, sB0 + 16384);
  WVM4;
  BARRIER();

  const int nt = K >> 6;          // >= 16, even
  #pragma unroll 1
  for (int t = 0; t < nt - 2; t += 2) {
    TILE4(t,     sA0,         sB0,         sA0 + 16384, sB0 + 16384, true, true, WVM8, WVM8);
    TILE4(t + 1, sA0 + 16384, sB0 + 16384, sA0,         sB0,         true, true, WVM8, WVM8);
  }
  // drain ladder: counts shrink as stages stop being issued
  TILE4(nt - 2, sA0,         sB0,         sA0 + 16384, sB0 + 16384, true,  false, WVM8, WVM4);
  TILE4(nt - 1, sA0 + 16384, sB0 + 16384, sA0,         sB0,         false, false, WVM0, WNONE);

  if (EPI == 0) {   // scatter bf16 to q/k/v (B,H,N,DH); col ranges 1024-aligned
    #pragma unroll
    for (int mf = 0; mf < 8; ++mf)
      #pragma unroll
      for (int nf = 0; nf < 4; ++nf)
        #pragma unroll
        for (int j = 0; j < 4; ++j) {
          int m = m0 + wm*128 + mf*16 + l4*4 + j;
          int gc = n0 + wn*64 + nf*16 + l15;
          int bufsel = gc >> 10, inner = gc & 1023, h = inner >> 7, d = inner & 127;
          u16* dst = bufsel == 0 ? Dq : (bufsel == 1 ? Dk : Dv);
          int b = m >> 12, n = m & (N_ - 1);
          dst[(((size_t)(b*H_ + h)*N_ + n) << 7) + d] = f2bf(acc[mf][nf][j]);
        }
  } else {          // f32 row-major
    #pragma unroll
    for (int mf = 0; mf < 8; ++mf)
      #pragma unroll
      for (int nf = 0; nf < 4; ++nf)
        #pragma unroll
        for (int j = 0; j < 4; ++j) {
          int m = m0 + wm*128 + mf*16 + l4*4 + j;
          int gc = n0 + wn*64 + nf*16 + l15;
          Cf[(size_t)m*Ncols + gc] = acc[mf][nf][j];
        }
  }
}

// ---------------- in-place qk L2-norm (+q_scale/k_scale, q folds SCALE=8) ----
__global__ __launch_bounds__(256) void normqk_kernel(
    u16* __restrict__ qb, u16* __restrict__ kb,
    const float* __restrict__ qs, const float* __restrict__ ks) {
  int lane = threadIdx.x & 63, wv = threadIdx.x >> 6;
  size_t vec = (size_t)blockIdx.x * 4 + wv;         // 0..131071
  bool isq = vec < 65536;
  u16* p = isq ? qb + vec*128 : kb + (vec - 65536)*128;
  const float* sc = isq ? qs : ks;
  u32 u = *(const u32*)(p + lane*2);
  float a = bf2f((u16)(u & 0xffffu));
  float b = bf2f((u16)(u >> 16));
  float ss = a*a + b*b;
  #pragma unroll
  for (int off = 32; off >= 1; off >>= 1) ss += __shfl_xor(ss, off);
  float inv = 1.0f / fmaxf(sqrtf(ss), 1e-12f);
  if (isq) inv *= 8.0f;                              // fold qk_scale SCALE
  float r0 = a * inv * sc[lane*2];
  float r1 = b * inv * sc[lane*2 + 1];
  *(u32*)(p + lane*2) = (u32)f2bf(r0) | ((u32)f2bf(r1) << 16);
}

// ---------------- V transpose: (B*H, N, 128) -> (B*H, 128, N) ----------------
__global__ __launch_bounds__(256) void transpose_v_kernel(
    const u16* __restrict__ v, u16* __restrict__ vT) {
  int bh = blockIdx.x >> 6;
  int n0 = (blockIdx.x & 63) << 6;                   // 64-row n tile
  __shared__ u16 tl[64][136];
  int tid = threadIdx.x;
  #pragma unroll
  for (int r = 0; r < 4; ++r) {
    int cf = r*256 + tid;
    int row = cf >> 4, ch = cf & 15;
    *(short8*)&tl[row][ch*8] = *(const short8*)(v + ((size_t)bh*N_ + n0 + row)*128 + ch*8);
  }
  __syncthreads();
  #pragma unroll
  for (int r = 0; r < 4; ++r) {
    int cf = r*256 + tid;
    int d = cf >> 3, nch = cf & 7;
    short8 o;
    #pragma unroll
    for (int i = 0; i < 8; ++i) o[i] = (short)tl[nch*8 + i][d];
    *(short8*)(vT + ((size_t)bh*128 + d)*N_ + n0 + nch*8) = o;
  }
}

// ---------------- gates: sigmoid(x @ Wg^T + bg), (B*N, 8) f32 ----------------
__global__ __launch_bounds__(256) void gates_kernel(
    const float* __restrict__ x, const float* __restrict__ Wg,
    const float* __restrict__ bg, float* __restrict__ gates) {
  int m = blockIdx.x;
  int tid = threadIdx.x;
  const float* xr = x + (size_t)m * D_;
  float acc[8] = {};
  for (int d = tid; d < D_; d += 256) {
    float xv = xr[d];
    #pragma unroll
    for (int h = 0; h < 8; ++h) acc[h] = fmaf(xv, Wg[h*D_ + d], acc[h]);
  }
  #pragma unroll
  for (int h = 0; h < 8; ++h)
    #pragma unroll
    for (int off = 32; off >= 1; off >>= 1) acc[h] += __shfl_xor(acc[h], off);
  __shared__ float red[4][8];
  int lane = tid & 63, wv = tid >> 6;
  if (lane == 0) {
    #pragma unroll
    for (int h = 0; h < 8; ++h) red[wv][h] = acc[h];
  }
  __syncthreads();
  if (tid < 8) {
    float vsum = red[0][tid] + red[1][tid] + red[2][tid] + red[3][tid] + bg[tid];
    gates[(size_t)m*8 + tid] = 1.0f / (1.0f + __expf(-vsum));
  }
}

// ---------------- windowed flash attention + gating -> o (B*N, 1024) bf16 ----
__global__ __launch_bounds__(256) void attn_kernel(
    const u16* __restrict__ q, const u16* __restrict__ k,
    const u16* __restrict__ vT, const float* __restrict__ gates,
    u16* __restrict__ o) {
  const int bid = blockIdx.x;
  const int t = bid & 3;
  const int c = (bid >> 2) & 7;
  const int bh = bid >> 5;
  const int b = bh >> 3, h = bh & 7;
  const int i0 = c*W_ + t*128;
  const int tid = threadIdx.x;
  const int lane = tid & 63, wv = tid >> 6;
  const int l15 = lane & 15, l4 = lane >> 4;

  __shared__ u16 sK[64*128];      // [key][d], 16-chunk XOR swizzle
  __shared__ u16 sV[128*64];      // [d][key], 8-chunk XOR swizzle
  __shared__ u16 sP[4][32*64];    // per-wave P, 8-chunk XOR swizzle

  short8 qf[2][4];
  const u16* qbase = q + (((size_t)bh*N_ + i0 + wv*32) << 7);
  #pragma unroll
  for (int mf = 0; mf < 2; ++mf)
    #pragma unroll
    for (int ks = 0; ks < 4; ++ks)
      qf[mf][ks] = *(const short8*)(qbase + (mf*16 + l15)*128 + ks*32 + l4*8);

  float mrow[2][4], lrow[2][4];
  f32x4 oacc[2][8];
  #pragma unroll
  for (int mf = 0; mf < 2; ++mf) {
    #pragma unroll
    for (int j = 0; j < 4; ++j) { mrow[mf][j] = -1e30f; lrow[mf][j] = 0.f; }
    #pragma unroll
    for (int df = 0; df < 8; ++df) oacc[mf][df] = (f32x4){0.f,0.f,0.f,0.f};
  }
  u16* sPw = &sP[wv][0];

  #pragma unroll 1
  for (int kt = 0; kt < 10; ++kt) {
    const int j0 = i0 - 512 + kt*64;
    if (j0 < 0) continue;                 // block-uniform
    __syncthreads();
    #pragma unroll
    for (int r = 0; r < 4; ++r) {         // stage K: 64 rows x 16 chunks
      int cf = r*256 + tid;
      int row = cf >> 4, cph = cf & 15;
      int clg = cph ^ (row & 15);
      GLOAD_LDS16(k + (((size_t)bh*N_ + j0 + row) << 7) + clg*8, sK + (size_t)(r*256 + wv*64)*8);
    }
    #pragma unroll
    for (int r = 0; r < 4; ++r) {         // stage V^T: 128 rows(d) x 8 chunks
      int cf = r*256 + tid;
      int row = cf >> 3, cph = cf & 7;
      int clg = cph ^ (row & 7);
      GLOAD_LDS16(vT + ((size_t)bh*128 + row)*N_ + j0 + clg*8, sV + (size_t)(r*256 + wv*64)*8);
    }
    __syncthreads();

    f32x4 s[2][4];
    #pragma unroll
    for (int mf = 0; mf < 2; ++mf)
      #pragma unroll
      for (int nf = 0; nf < 4; ++nf) s[mf][nf] = (f32x4){0.f,0.f,0.f,0.f};
    #pragma unroll
    for (int ks = 0; ks < 4; ++ks) {
      short8 kb[4];
      #pragma unroll
      for (int nf = 0; nf < 4; ++nf) {
        int row = nf*16 + l15;
        int ch = (ks*4 + l4) ^ (row & 15);
        kb[nf] = *(const short8*)(sK + row*128 + ch*8);
      }
      #pragma unroll
      for (int mf = 0; mf < 2; ++mf)
        #pragma unroll
        for (int nf = 0; nf < 4; ++nf)
          s[mf][nf] = mfma16(qf[mf][ks], kb[nf], s[mf][nf]);
    }

    if (kt < 2 || kt > 7) {
      #pragma unroll
      for (int mf = 0; mf < 2; ++mf)
        #pragma unroll
        for (int nf = 0; nf < 4; ++nf)
          #pragma unroll
          for (int j = 0; j < 4; ++j) {
            int r = wv*32 + mf*16 + l4*4 + j;
            int sidx = nf*16 + l15;
            int dist = (i0 + r) - (j0 + sidx);
            if (dist < 0 || dist > 512) s[mf][nf][j] = -1e30f;
          }
    }

    #pragma unroll
    for (int mf = 0; mf < 2; ++mf) {
      #pragma unroll
      for (int j = 0; j < 4; ++j) {
        float mx = fmaxf(fmaxf(s[mf][0][j], s[mf][1][j]), fmaxf(s[mf][2][j], s[mf][3][j]));
        #pragma unroll
        for (int off = 1; off <= 8; off <<= 1) mx = fmaxf(mx, __shfl_xor(mx, off));
        float mnew = fmaxf(mrow[mf][j], mx);
        float scal = __expf(mrow[mf][j] - mnew);
        mrow[mf][j] = mnew;
        float ls = 0.f;
        #pragma unroll
        for (int nf = 0; nf < 4; ++nf) {
          float p = __expf(s[mf][nf][j] - mnew);
          s[mf][nf][j] = p;
          ls += p;
        }
        #pragma unroll
        for (int off = 1; off <= 8; off <<= 1) ls += __shfl_xor(ls, off);
        lrow[mf][j] = lrow[mf][j]*scal + ls;
        #pragma unroll
        for (int df = 0; df < 8; ++df) oacc[mf][df][j] *= scal;
        int prow = mf*16 + l4*4 + j;
        #pragma unroll
        for (int nf = 0; nf < 4; ++nf) {
          int pcol = nf*16 + l15;
          int ch = (pcol >> 3) ^ (prow & 7);
          sPw[prow*64 + ch*8 + (pcol & 7)] = f2bf(s[mf][nf][j]);
        }
      }
    }

    #pragma unroll
    for (int ks2 = 0; ks2 < 2; ++ks2) {
      short8 pa[2];
      #pragma unroll
      for (int mf = 0; mf < 2; ++mf) {
        int prow = mf*16 + l15;
        int ch = (ks2*4 + l4) ^ (prow & 7);
        pa[mf] = *(const short8*)(sPw + prow*64 + ch*8);
      }
      #pragma unroll
      for (int df = 0; df < 8; ++df) {
        int vd = df*16 + l15;
        int ch2 = (ks2*4 + l4) ^ (vd & 7);
        short8 vb = *(const short8*)(sV + vd*64 + ch2*8);
        #pragma unroll
        for (int mf = 0; mf < 2; ++mf)
          oacc[mf][df] = mfma16(pa[mf], vb, oacc[mf][df]);
      }
    }
  }

  #pragma unroll
  for (int mf = 0; mf < 2; ++mf)
    #pragma unroll
    for (int j = 0; j < 4; ++j) {
      int r = wv*32 + mf*16 + l4*4 + j;
      int i = i0 + r;
      float f = (1.0f / lrow[mf][j]) * gates[((size_t)b*N_ + i)*8 + h];
      #pragma unroll
      for (int df = 0; df < 8; ++df)
        o[((size_t)b*N_ + i)*INNER_ + h*128 + df*16 + l15] = f2bf(oacc[mf][df][j] * f);
    }
}

// ---------------------------------------------------------------------------
extern "C" void kernel_launch(void* const* d_in, const int* in_sizes, int n_in,
                              void* d_out, int out_size, void* d_ws, size_t ws_size,
                              hipStream_t stream) {
  const float* x       = (const float*)d_in[0];
  const float* Wq      = (const float*)d_in[1];
  const float* Wkv     = (const float*)d_in[2];
  const float* q_scale = (const float*)d_in[3];
  const float* k_scale = (const float*)d_in[4];
  const float* Wg      = (const float*)d_in[5];
  const float* bg      = (const float*)d_in[6];
  const float* Wo      = (const float*)d_in[7];
  float* out = (float*)d_out;

  u16* qb  = (u16*)d_out;            // q,k,v,vT inside d_out (67,108,864 B)
  u16* kb  = qb + 8388608;
  u16* vb  = kb + 8388608;
  u16* vTb = vb + 8388608;

  char* w = (char*)d_ws;
  u16* xb   = (u16*)w;               // 33,554,432 B
  u16* ob   = (u16*)w;               // aliases xb (xb dead after QKV gemm)
  u16* Wcat = (u16*)(w + 33554432);  // 12,582,912 B
  u16* Wob  = (u16*)(w + 46137344);  // 4,194,304 B
  float* gb = (float*)(w + 50331648);// 262,144 B
  (void)in_sizes; (void)n_in; (void)out_size; (void)ws_size;

  hipFuncSetAttribute((const void*)gemm256<0>,
                      hipFuncAttributeMaxDynamicSharedMemorySize, 131072);
  hipFuncSetAttribute((const void*)gemm256<1>,
                      hipFuncAttributeMaxDynamicSharedMemorySize, 131072);

  cvt_kernel<<<12288, 256, 0, stream>>>(x, Wq, Wkv, Wo, xb, Wcat, Wob);
  gemm256<0><<<384, 512, 131072, stream>>>(xb, Wcat, qb, kb, vb, nullptr, 3072, 2048);
  normqk_kernel<<<32768, 256, 0, stream>>>(qb, kb, q_scale, k_scale);
  transpose_v_kernel<<<1024, 256, 0, stream>>>(vb, vTb);
  gates_kernel<<<8192, 256, 0, stream>>>(x, Wg, bg, gb);
  attn_kernel<<<512, 256, 0, stream>>>(qb, kb, vTb, gb, ob);
  gemm256<1><<<256, 512, 131072, stream>>>(ob, Wob, nullptr, nullptr, nullptr, out, 2048, 1024);
}

// Round 4
// 306.660 us; speedup vs baseline: 1.0153x; 1.0153x over previous
//
#include <hip/hip_runtime.h>
#include <hip/hip_bf16.h>
#include <cstdint>

typedef short short8 __attribute__((ext_vector_type(8)));
typedef __bf16 bf16x8 __attribute__((ext_vector_type(8)));
typedef float f32x4 __attribute__((ext_vector_type(4)));
typedef unsigned short u16;
typedef unsigned int u32;

#define B_  2
#define N_  4096
#define D_  2048
#define H_  8
#define DH_ 128
#define W_  512
#define M_  (B_*N_)      // 8192
#define INNER_ (H_*DH_)  // 1024

static __device__ __forceinline__ u16 f2bf(float f) {
  u32 u = __float_as_uint(f);
  u32 r = (u + 0x7fffu + ((u >> 16) & 1u)) >> 16;   // RNE
  return (u16)r;
}
static __device__ __forceinline__ float bf2f(u16 u) {
  return __uint_as_float(((u32)u) << 16);
}
static __device__ __forceinline__ f32x4 mfma16(short8 a, short8 b, f32x4 c) {
  return __builtin_amdgcn_mfma_f32_16x16x32_bf16(
      __builtin_bit_cast(bf16x8, a), __builtin_bit_cast(bf16x8, b), c, 0, 0, 0);
}

#define GLOAD_LDS16(g, s) \
  __builtin_amdgcn_global_load_lds((const __attribute__((address_space(1))) void*)(g), \
                                   (__attribute__((address_space(3))) void*)(s), 16, 0, 0)

// ---------------- convert f32 -> bf16 (x, Wq|Wkv concat, Wo) ----------------
__global__ __launch_bounds__(256) void cvt_kernel(
    const float* __restrict__ x, const float* __restrict__ Wq,
    const float* __restrict__ Wkv, const float* __restrict__ Wo,
    u16* __restrict__ xb, u16* __restrict__ Wcat, u16* __restrict__ Wob) {
  size_t i = ((size_t)blockIdx.x * 256 + threadIdx.x) * 8;
  const float* src; u16* dst; size_t off;
  const size_t SX = 16777216ul, SQ = 2097152ul, SKV = 4194304ul;
  if (i < SX)                { src = x;   dst = xb;             off = i; }
  else if (i < SX+SQ)        { src = Wq;  dst = Wcat;           off = i - SX; }
  else if (i < SX+SQ+SKV)    { src = Wkv; dst = Wcat + 2097152; off = i - SX - SQ; }
  else                       { src = Wo;  dst = Wob;            off = i - SX - SQ - SKV; }
  float4 a = *(const float4*)(src + off);
  float4 b = *(const float4*)(src + off + 4);
  short8 o;
  o[0]=(short)f2bf(a.x); o[1]=(short)f2bf(a.y); o[2]=(short)f2bf(a.z); o[3]=(short)f2bf(a.w);
  o[4]=(short)f2bf(b.x); o[5]=(short)f2bf(b.y); o[6]=(short)f2bf(b.z); o[7]=(short)f2bf(b.w);
  *(short8*)(dst + off) = o;
}

// ================= 256x256 8-phase bf16 GEMM, C = A(MxK) * Bw(NxK)^T ========
// 512 thr / 8 waves (2M x 4N). BK=64 in two K-halves of 32.
// LDS: [buf][kh] 256x32 per operand, 128 KiB. REGISTER double-buffered frags:
// each phase issues NEXT phase's ds_reads (compiler emits counted lgkmcnt(4/8),
// never 0); MFMA consumes frags loaded one phase earlier. vmcnt placed before
// the closing barrier of ph1/ph3 so every wave's wait precedes the shared
// barrier ahead of the dependent cross-wave LDS read.
#define BARRIER() __builtin_amdgcn_s_barrier()
#define SB0 __builtin_amdgcn_sched_barrier(0)
#define WVM6 asm volatile("s_waitcnt vmcnt(6)" ::: "memory")
#define WVM4 asm volatile("s_waitcnt vmcnt(4)" ::: "memory")
#define WVM0 asm volatile("s_waitcnt vmcnt(0)" ::: "memory")
#define WNONE ((void)0)

// stage one 256x32 half-tile (16 KB): per thread 2 x global_load_lds(16B).
#define STAGE_HALF(gbase, sreg) do { \
    const u16* _g = (gbase) + _cs; \
    GLOAD_LDS16(_g + (size_t)(wv*32 + (lane>>2))*K,      (sreg) + wv*1024); \
    GLOAD_LDS16(_g + (size_t)(wv*32 + 16 + (lane>>2))*K, (sreg) + wv*1024 + 512); \
  } while(0)

#define DSA4(dst, sbase, mfb) do { \
    _Pragma("unroll") for (int q = 0; q < 4; ++q) \
      dst[q] = *(const short8*)((sbase) + (wm*128 + ((mfb)+q)*16 + l15)*32 + fch); \
  } while(0)
#define DSB4(dst, sbase) do { \
    _Pragma("unroll") for (int q = 0; q < 4; ++q) \
      dst[q] = *(const short8*)((sbase) + (wn*64 + q*16 + l15)*32 + fch); \
  } while(0)

#define MM16(afr, bfr, mfb) do { \
    __builtin_amdgcn_s_setprio(1); \
    _Pragma("unroll") for (int q = 0; q < 4; ++q) \
      _Pragma("unroll") for (int nf = 0; nf < 4; ++nf) \
        acc[(mfb)+q][nf] = mfma16(afr[q], bfr[nf], acc[(mfb)+q][nf]); \
    __builtin_amdgcn_s_setprio(0); \
  } while(0)

// One K-tile T = 4 phases. MFMA(phX) consumes frags loaded in phase X-1.
// ph1 MFMA: A[T,kh0,mf0-3]xB[T,kh0] (loaded prev ph4); reads A[T,kh0,mf4-7]
// ph2 MFMA: A[T,kh0,mf4-7]xB[T,kh0]; reads A[T,kh1,mf0-3]+B[T,kh1]
// ph3 MFMA: A[T,kh1,mf0-3]xB[T,kh1]; reads A[T,kh1,mf4-7]
// ph4 MFMA: A[T,kh1,mf4-7]xB[T,kh1]; reads A[T+1,kh0,mf0-3]+B[T+1,kh0] (P4)
// C1 stages T+1's kh1; C2 stages T+2's kh0. V1 guards T's kh1 staging;
// V3 guards T+1's kh0 staging (both executed by ALL waves before the barrier).
#define TILE4(T, SA_C, SB_C, SA_N, SB_N, C1, C2, P4, V1, V3) do { \
    const u16* gAt = gA + (size_t)(T)*64; \
    const u16* gBt = gB + (size_t)(T)*64; \
    DSA4(afn, SA_C, 4); \
    if (C1) STAGE_HALF(gAt + 96, (SA_N) + 8192); \
    SB0; BARRIER(); \
    MM16(afc, bfc, 0); \
    V1; BARRIER(); \
    DSA4(afc, (SA_C) + 8192, 0); DSB4(bfn, (SB_C) + 8192); \
    if (C1) STAGE_HALF(gBt + 96, (SB_N) + 8192); \
    SB0; BARRIER(); \
    MM16(afn, bfc, 4); \
    BARRIER(); \
    DSA4(afn, (SA_C) + 8192, 4); \
    if (C2) STAGE_HALF(gAt + 128, SA_C); \
    SB0; BARRIER(); \
    MM16(afc, bfn, 0); \
    V3; BARRIER(); \
    if (P4) { DSA4(afc, SA_N, 0); DSB4(bfc, SB_N); } \
    if (C2) STAGE_HALF(gBt + 128, SB_C); \
    SB0; BARRIER(); \
    MM16(afn, bfn, 4); \
    BARRIER(); \
  } while(0)

template<int EPI>
__global__ __launch_bounds__(512, 2) void gemm256(
    const u16* __restrict__ A, const u16* __restrict__ Bw,
    u16* __restrict__ Dq, u16* __restrict__ Dk, u16* __restrict__ Dv,
    float* __restrict__ Cf, int Ncols, int K) {
  extern __shared__ u16 lds[];
  const int tid = threadIdx.x;
  const int lane = tid & 63, wv = tid >> 6;
  const int wm = wv >> 2, wn = wv & 3;
  const int l15 = lane & 15, l4 = lane >> 4;

  // bijective XCD swizzle (gridDim.x % 8 == 0)
  const int nwg = gridDim.x;
  const int swz = (blockIdx.x & 7) * (nwg >> 3) + (blockIdx.x >> 3);
  const int by = swz & 31;                  // M/256 = 32 tiles
  const int bx = swz >> 5;
  const int m0 = by << 8, n0 = bx << 8;

  const u16* gA = A + (size_t)m0 * K;
  const u16* gB = Bw + (size_t)n0 * K;
  u16* sA0 = lds;                 // [buf][kh] stride 8192 u16 (16 KB)
  u16* sB0 = lds + 32768;

  const int _cs = ((lane & 3) ^ ((lane >> 3) & 3)) * 8;  // stage src pre-swizzle
  const int fch = (l4 ^ ((l15 >> 1) & 3)) * 8;           // frag read deswizzle

  f32x4 acc[8][4] = {};
  short8 afc[4], afn[4], bfc[4], bfn[4];

  // prologue: stage T0{kh0,kh1}, T1{kh0} (12 loads); own-wave vmcnt(8) covers
  // T0kh0; barrier publishes cross-wave; then prefetch ph1 frags.
  STAGE_HALF(gA,      sA0);
  STAGE_HALF(gB,      sB0);
  STAGE_HALF(gA + 32, sA0 + 8192);
  STAGE_HALF(gB + 32, sB0 + 8192);
  STAGE_HALF(gA + 64, sA0 + 16384);
  STAGE_HALF(gB + 64, sB0 + 16384);
  asm volatile("s_waitcnt vmcnt(8)" ::: "memory");
  BARRIER();
  DSA4(afc, sA0, 0); DSB4(bfc, sB0);
  SB0;

  const int nt = K >> 6;          // 32 (QKV) / 16 (proj), even, >= 4
  #pragma unroll 1
  for (int t = 0; t < nt - 2; t += 2) {
    TILE4(t,     sA0,         sB0,         sA0 + 16384, sB0 + 16384, true, true, true, WVM6, WVM6);
    TILE4(t + 1, sA0 + 16384, sB0 + 16384, sA0,         sB0,         true, true, true, WVM6, WVM6);
  }
  // drain: nt-2 stages only T+1 kh1; nt-1 stages nothing, no ph4 prefetch
  TILE4(nt - 2, sA0,         sB0,         sA0 + 16384, sB0 + 16384, true,  false, true,  WVM6, WVM4);
  TILE4(nt - 1, sA0 + 16384, sB0 + 16384, sA0,         sB0,         false, false, false, WVM0, WNONE);

  if (EPI == 0) {   // scatter bf16 to q/k/v (B,H,N,DH); col ranges 1024-aligned
    #pragma unroll
    for (int mf = 0; mf < 8; ++mf)
      #pragma unroll
      for (int nf = 0; nf < 4; ++nf)
        #pragma unroll
        for (int j = 0; j < 4; ++j) {
          int m = m0 + wm*128 + mf*16 + l4*4 + j;
          int gc = n0 + wn*64 + nf*16 + l15;
          int bufsel = gc >> 10, inner = gc & 1023, h = inner >> 7, d = inner & 127;
          u16* dst = bufsel == 0 ? Dq : (bufsel == 1 ? Dk : Dv);
          int b = m >> 12, n = m & (N_ - 1);
          dst[(((size_t)(b*H_ + h)*N_ + n) << 7) + d] = f2bf(acc[mf][nf][j]);
        }
  } else {          // f32 row-major
    #pragma unroll
    for (int mf = 0; mf < 8; ++mf)
      #pragma unroll
      for (int nf = 0; nf < 4; ++nf)
        #pragma unroll
        for (int j = 0; j < 4; ++j) {
          int m = m0 + wm*128 + mf*16 + l4*4 + j;
          int gc = n0 + wn*64 + nf*16 + l15;
          Cf[(size_t)m*Ncols + gc] = acc[mf][nf][j];
        }
  }
}

// ---------------- in-place qk L2-norm (+q_scale/k_scale, q folds SCALE=8) ----
__global__ __launch_bounds__(256) void normqk_kernel(
    u16* __restrict__ qb, u16* __restrict__ kb,
    const float* __restrict__ qs, const float* __restrict__ ks) {
  int lane = threadIdx.x & 63, wv = threadIdx.x >> 6;
  size_t vec = (size_t)blockIdx.x * 4 + wv;         // 0..131071
  bool isq = vec < 65536;
  u16* p = isq ? qb + vec*128 : kb + (vec - 65536)*128;
  const float* sc = isq ? qs : ks;
  u32 u = *(const u32*)(p + lane*2);
  float a = bf2f((u16)(u & 0xffffu));
  float b = bf2f((u16)(u >> 16));
  float ss = a*a + b*b;
  #pragma unroll
  for (int off = 32; off >= 1; off >>= 1) ss += __shfl_xor(ss, off);
  float inv = 1.0f / fmaxf(sqrtf(ss), 1e-12f);
  if (isq) inv *= 8.0f;                              // fold qk_scale SCALE
  float r0 = a * inv * sc[lane*2];
  float r1 = b * inv * sc[lane*2 + 1];
  *(u32*)(p + lane*2) = (u32)f2bf(r0) | ((u32)f2bf(r1) << 16);
}

// ---------------- V transpose: (B*H, N, 128) -> (B*H, 128, N) ----------------
__global__ __launch_bounds__(256) void transpose_v_kernel(
    const u16* __restrict__ v, u16* __restrict__ vT) {
  int bh = blockIdx.x >> 6;
  int n0 = (blockIdx.x & 63) << 6;                   // 64-row n tile
  __shared__ u16 tl[64][136];
  int tid = threadIdx.x;
  #pragma unroll
  for (int r = 0; r < 4; ++r) {
    int cf = r*256 + tid;
    int row = cf >> 4, ch = cf & 15;
    *(short8*)&tl[row][ch*8] = *(const short8*)(v + ((size_t)bh*N_ + n0 + row)*128 + ch*8);
  }
  __syncthreads();
  #pragma unroll
  for (int r = 0; r < 4; ++r) {
    int cf = r*256 + tid;
    int d = cf >> 3, nch = cf & 7;
    short8 o;
    #pragma unroll
    for (int i = 0; i < 8; ++i) o[i] = (short)tl[nch*8 + i][d];
    *(short8*)(vT + ((size_t)bh*128 + d)*N_ + n0 + nch*8) = o;
  }
}

// ---------------- gates: sigmoid(xb @ Wg^T + bg), (B*N, 8) f32 (bf16 input) --
__global__ __launch_bounds__(256) void gates_kernel(
    const u16* __restrict__ xb, const float* __restrict__ Wg,
    const float* __restrict__ bg, float* __restrict__ gates) {
  int m = blockIdx.x;
  int tid = threadIdx.x;
  const u16* xr = xb + (size_t)m * D_;
  float acc[8] = {};
  for (int d0 = tid*8; d0 < D_; d0 += 256*8) {
    short8 xv8 = *(const short8*)(xr + d0);
    #pragma unroll
    for (int e = 0; e < 8; ++e) {
      float xv = bf2f((u16)xv8[e]);
      #pragma unroll
      for (int h = 0; h < 8; ++h) acc[h] = fmaf(xv, Wg[h*D_ + d0 + e], acc[h]);
    }
  }
  #pragma unroll
  for (int h = 0; h < 8; ++h)
    #pragma unroll
    for (int off = 32; off >= 1; off >>= 1) acc[h] += __shfl_xor(acc[h], off);
  __shared__ float red[4][8];
  int lane = tid & 63, wv = tid >> 6;
  if (lane == 0) {
    #pragma unroll
    for (int h = 0; h < 8; ++h) red[wv][h] = acc[h];
  }
  __syncthreads();
  if (tid < 8) {
    float vsum = red[0][tid] + red[1][tid] + red[2][tid] + red[3][tid] + bg[tid];
    gates[(size_t)m*8 + tid] = 1.0f / (1.0f + __expf(-vsum));
  }
}

// ---------------- windowed flash attention + gating -> o (B*N, 1024) bf16 ----
__global__ __launch_bounds__(256) void attn_kernel(
    const u16* __restrict__ q, const u16* __restrict__ k,
    const u16* __restrict__ vT, const float* __restrict__ gates,
    u16* __restrict__ o) {
  const int bid = blockIdx.x;
  const int t = bid & 3;
  const int c = (bid >> 2) & 7;
  const int bh = bid >> 5;
  const int b = bh >> 3, h = bh & 7;
  const int i0 = c*W_ + t*128;
  const int tid = threadIdx.x;
  const int lane = tid & 63, wv = tid >> 6;
  const int l15 = lane & 15, l4 = lane >> 4;

  __shared__ u16 sK[64*128];      // [key][d], 16-chunk XOR swizzle
  __shared__ u16 sV[128*64];      // [d][key], 8-chunk XOR swizzle
  __shared__ u16 sP[4][32*64];    // per-wave P, 8-chunk XOR swizzle

  short8 qf[2][4];
  const u16* qbase = q + (((size_t)bh*N_ + i0 + wv*32) << 7);
  #pragma unroll
  for (int mf = 0; mf < 2; ++mf)
    #pragma unroll
    for (int ks = 0; ks < 4; ++ks)
      qf[mf][ks] = *(const short8*)(qbase + (mf*16 + l15)*128 + ks*32 + l4*8);

  float mrow[2][4], lrow[2][4];
  f32x4 oacc[2][8];
  #pragma unroll
  for (int mf = 0; mf < 2; ++mf) {
    #pragma unroll
    for (int j = 0; j < 4; ++j) { mrow[mf][j] = -1e30f; lrow[mf][j] = 0.f; }
    #pragma unroll
    for (int df = 0; df < 8; ++df) oacc[mf][df] = (f32x4){0.f,0.f,0.f,0.f};
  }
  u16* sPw = &sP[wv][0];

  #pragma unroll 1
  for (int kt = 0; kt < 10; ++kt) {
    const int j0 = i0 - 512 + kt*64;
    if (j0 < 0) continue;                 // block-uniform
    __syncthreads();
    #pragma unroll
    for (int r = 0; r < 4; ++r) {         // stage K: 64 rows x 16 chunks
      int cf = r*256 + tid;
      int row = cf >> 4, cph = cf & 15;
      int clg = cph ^ (row & 15);
      GLOAD_LDS16(k + (((size_t)bh*N_ + j0 + row) << 7) + clg*8, sK + (size_t)(r*256 + wv*64)*8);
    }
    #pragma unroll
    for (int r = 0; r < 4; ++r) {         // stage V^T: 128 rows(d) x 8 chunks
      int cf = r*256 + tid;
      int row = cf >> 3, cph = cf & 7;
      int clg = cph ^ (row & 7);
      GLOAD_LDS16(vT + ((size_t)bh*128 + row)*N_ + j0 + clg*8, sV + (size_t)(r*256 + wv*64)*8);
    }
    __syncthreads();

    f32x4 s[2][4];
    #pragma unroll
    for (int mf = 0; mf < 2; ++mf)
      #pragma unroll
      for (int nf = 0; nf < 4; ++nf) s[mf][nf] = (f32x4){0.f,0.f,0.f,0.f};
    #pragma unroll
    for (int ks = 0; ks < 4; ++ks) {
      short8 kb[4];
      #pragma unroll
      for (int nf = 0; nf < 4; ++nf) {
        int row = nf*16 + l15;
        int ch = (ks*4 + l4) ^ (row & 15);
        kb[nf] = *(const short8*)(sK + row*128 + ch*8);
      }
      #pragma unroll
      for (int mf = 0; mf < 2; ++mf)
        #pragma unroll
        for (int nf = 0; nf < 4; ++nf)
          s[mf][nf] = mfma16(qf[mf][ks], kb[nf], s[mf][nf]);
    }

    if (kt < 2 || kt > 7) {
      #pragma unroll
      for (int mf = 0; mf < 2; ++mf)
        #pragma unroll
        for (int nf = 0; nf < 4; ++nf)
          #pragma unroll
          for (int j = 0; j < 4; ++j) {
            int r = wv*32 + mf*16 + l4*4 + j;
            int sidx = nf*16 + l15;
            int dist = (i0 + r) - (j0 + sidx);
            if (dist < 0 || dist > 512) s[mf][nf][j] = -1e30f;
          }
    }

    #pragma unroll
    for (int mf = 0; mf < 2; ++mf) {
      #pragma unroll
      for (int j = 0; j < 4; ++j) {
        float mx = fmaxf(fmaxf(s[mf][0][j], s[mf][1][j]), fmaxf(s[mf][2][j], s[mf][3][j]));
        #pragma unroll
        for (int off = 1; off <= 8; off <<= 1) mx = fmaxf(mx, __shfl_xor(mx, off));
        float mnew = fmaxf(mrow[mf][j], mx);
        float scal = __expf(mrow[mf][j] - mnew);
        mrow[mf][j] = mnew;
        float ls = 0.f;
        #pragma unroll
        for (int nf = 0; nf < 4; ++nf) {
          float p = __expf(s[mf][nf][j] - mnew);
          s[mf][nf][j] = p;
          ls += p;
        }
        #pragma unroll
        for (int off = 1; off <= 8; off <<= 1) ls += __shfl_xor(ls, off);
        lrow[mf][j] = lrow[mf][j]*scal + ls;
        #pragma unroll
        for (int df = 0; df < 8; ++df) oacc[mf][df][j] *= scal;
        int prow = mf*16 + l4*4 + j;
        #pragma unroll
        for (int nf = 0; nf < 4; ++nf) {
          int pcol = nf*16 + l15;
          int ch = (pcol >> 3) ^ (prow & 7);
          sPw[prow*64 + ch*8 + (pcol & 7)] = f2bf(s[mf][nf][j]);
        }
      }
    }

    #pragma unroll
    for (int ks2 = 0; ks2 < 2; ++ks2) {
      short8 pa[2];
      #pragma unroll
      for (int mf = 0; mf < 2; ++mf) {
        int prow = mf*16 + l15;
        int ch = (ks2*4 + l4) ^ (prow & 7);
        pa[mf] = *(const short8*)(sPw + prow*64 + ch*8);
      }
      #pragma unroll
      for (int df = 0; df < 8; ++df) {
        int vd = df*16 + l15;
        int ch2 = (ks2*4 + l4) ^ (vd & 7);
        short8 vb = *(const short8*)(sV + vd*64 + ch2*8);
        #pragma unroll
        for (int mf = 0; mf < 2; ++mf)
          oacc[mf][df] = mfma16(pa[mf], vb, oacc[mf][df]);
      }
    }
  }

  #pragma unroll
  for (int mf = 0; mf < 2; ++mf)
    #pragma unroll
    for (int j = 0; j < 4; ++j) {
      int r = wv*32 + mf*16 + l4*4 + j;
      int i = i0 + r;
      float f = (1.0f / lrow[mf][j]) * gates[((size_t)b*N_ + i)*8 + h];
      #pragma unroll
      for (int df = 0; df < 8; ++df)
        o[((size_t)b*N_ + i)*INNER_ + h*128 + df*16 + l15] = f2bf(oacc[mf][df][j] * f);
    }
}

// ---------------------------------------------------------------------------
extern "C" void kernel_launch(void* const* d_in, const int* in_sizes, int n_in,
                              void* d_out, int out_size, void* d_ws, size_t ws_size,
                              hipStream_t stream) {
  const float* x       = (const float*)d_in[0];
  const float* Wq      = (const float*)d_in[1];
  const float* Wkv     = (const float*)d_in[2];
  const float* q_scale = (const float*)d_in[3];
  const float* k_scale = (const float*)d_in[4];
  const float* Wg      = (const float*)d_in[5];
  const float* bg      = (const float*)d_in[6];
  const float* Wo      = (const float*)d_in[7];
  float* out = (float*)d_out;

  u16* qb  = (u16*)d_out;            // q,k,v,vT inside d_out (67,108,864 B)
  u16* kb  = qb + 8388608;
  u16* vb  = kb + 8388608;
  u16* vTb = vb + 8388608;

  char* w = (char*)d_ws;
  u16* xb   = (u16*)w;               // 33,554,432 B
  u16* ob   = (u16*)w;               // aliases xb (xb dead after QKV gemm+gates)
  u16* Wcat = (u16*)(w + 33554432);  // 12,582,912 B
  u16* Wob  = (u16*)(w + 46137344);  // 4,194,304 B
  float* gb = (float*)(w + 50331648);// 262,144 B
  (void)in_sizes; (void)n_in; (void)out_size; (void)ws_size;

  hipFuncSetAttribute((const void*)gemm256<0>,
                      hipFuncAttributeMaxDynamicSharedMemorySize, 131072);
  hipFuncSetAttribute((const void*)gemm256<1>,
                      hipFuncAttributeMaxDynamicSharedMemorySize, 131072);

  cvt_kernel<<<12288, 256, 0, stream>>>(x, Wq, Wkv, Wo, xb, Wcat, Wob);
  gemm256<0><<<384, 512, 131072, stream>>>(xb, Wcat, qb, kb, vb, nullptr, 3072, 2048);
  normqk_kernel<<<32768, 256, 0, stream>>>(qb, kb, q_scale, k_scale);
  transpose_v_kernel<<<1024, 256, 0, stream>>>(vb, vTb);
  gates_kernel<<<8192, 256, 0, stream>>>(xb, Wg, bg, gb);
  attn_kernel<<<512, 256, 0, stream>>>(qb, kb, vTb, gb, ob);
  gemm256<1><<<256, 512, 131072, stream>>>(ob, Wob, nullptr, nullptr, nullptr, out, 2048, 1024);
}